// Round 4
// baseline (32569.962 us; speedup 1.0000x reference)
//
#include <hip/hip_runtime.h>
#include <hip/hip_bf16.h>

// ---------------------------------------------------------------------------
// MA_LSTM on MI355X (gfx950): persistent cooperative kernel, 256 blocks,
// 3 grid barriers per timestep.
//   P1 (256 blk = 64 Ngroups x 4 Kchunks): zpart[j] = chunk_j of
//       x@Wk(+bias) + h@Wr + c@Wc   (bf16 MFMA, hi/lo split of h,c)
//       waves: 2-way M x 2-way K split, 20KB LDS cross-wave reduce
//   P2 (64 blk, 1 wave each): cumsoftmax gates row-wise -> obuf (bf16)
//   P3 (64 blk): f=sigmoid(O@agg); c'=f*c+(1-f)*tanh(z4); h'=z3*tanh(c')
// ---------------------------------------------------------------------------

typedef short  bf16x8 __attribute__((ext_vector_type(8)));
typedef float  f32x4  __attribute__((ext_vector_type(4)));
typedef __hip_bfloat16 bf16;

#define U 1024
#define BATCH 64
#define TSTEPS 128
#define DIM 256
#define N5 5120
#define K2 2048
#define NBLK 256
#define ZP (BATCH * N5)          // elements per z-partial

// ---- workspace layout (bytes), high-water 36.31 MB ----
#define OFF_WRC   0u             // bf16 [5120][2048]  (Wr^T | Wc^T)
#define OFF_KT    20971520u      // bf16 [5120][256]   kernel^T
#define OFF_AGGT  23592960u      // bf16 [1024][3072]  aggregation^T
#define OFF_ZPART 29884416u      // f32  [4][64][5120]
#define OFF_ABUF  35127296u      // bf16 [4][64][1024] h_hi,h_lo,c_hi,c_lo
#define OFF_C32   35651584u      // f32  [64][1024]
#define OFF_OBUF  35913728u      // bf16 [64][3072]
#define OFF_SCAL  36306944u      // f32  [8]
#define OFF_SYNC  36307008u      // u32  [16]

// ---------------------------------------------------------------------------
__global__ __launch_bounds__(256) void k_transpose(const float* __restrict__ in,
                                                   bf16* __restrict__ out,
                                                   int C, int out_stride, int out_off) {
    __shared__ bf16 tile[64][65];
    const int tc = blockIdx.x * 64, tr = blockIdx.y * 64;
    const int tx = threadIdx.x & 63, ty0 = threadIdx.x >> 6;
#pragma unroll
    for (int i = 0; i < 64; i += 4)
        tile[ty0 + i][tx] = __float2bfloat16(in[(tr + ty0 + i) * C + tc + tx]);
    __syncthreads();
#pragma unroll
    for (int i = 0; i < 64; i += 4)
        out[(tc + ty0 + i) * out_stride + out_off + tr + tx] = tile[tx][ty0 + i];
}

struct AttPtrs { const float* p[12]; };

__global__ __launch_bounds__(256) void k_scal(AttPtrs ap, float* __restrict__ scal) {
    __shared__ float red[256];
    const int tid = threadIdx.x;
    for (int q = 0; q < 6; ++q) {
        const float* l = ap.p[2 * q];
        const float* r = ap.p[2 * q + 1];
        float s = 0.f;
        for (int i = tid; i < 1024; i += 256) s += l[i] * r[i];
        red[tid] = s; __syncthreads();
        for (int o = 128; o > 0; o >>= 1) {
            if (tid < o) red[tid] += red[tid + o];
            __syncthreads();
        }
        if (tid == 0) scal[q] = red[0];
        __syncthreads();
    }
}

// ---------------------------------------------------------------------------
__device__ __forceinline__ void gsync(unsigned* cnt, int tid, unsigned target) {
    __syncthreads();
    if (tid == 0) {
        __threadfence();  // release: flush this block's global writes
        __hip_atomic_fetch_add(cnt, 1u, __ATOMIC_RELEASE, __HIP_MEMORY_SCOPE_AGENT);
        while (__hip_atomic_load(cnt, __ATOMIC_ACQUIRE, __HIP_MEMORY_SCOPE_AGENT) < target)
            __builtin_amdgcn_s_sleep(2);
        __threadfence();  // acquire: invalidate stale cached lines
    }
    __syncthreads();
}

__device__ __forceinline__ float wave_sum(float v) {
#pragma unroll
    for (int o = 32; o > 0; o >>= 1) v += __shfl_xor(v, o, 64);
    return v;
}
__device__ __forceinline__ float wave_max(float v) {
#pragma unroll
    for (int o = 32; o > 0; o >>= 1) v = fmaxf(v, __shfl_xor(v, o, 64));
    return v;
}
__device__ __forceinline__ float wave_scan(float v, int lane) {
#pragma unroll
    for (int o = 1; o < 64; o <<= 1) {
        float n = __shfl_up(v, o, 64);
        if (lane >= o) v += n;
    }
    return v;
}
__device__ __forceinline__ float sigm(float x) { return 1.f / (1.f + __expf(-x)); }

__device__ __forceinline__ bf16x8 cvt8(const float* p) {
    const float4 a = *(const float4*)p;
    const float4 b = *(const float4*)(p + 4);
    bf16 t[8] = {__float2bfloat16(a.x), __float2bfloat16(a.y),
                 __float2bfloat16(a.z), __float2bfloat16(a.w),
                 __float2bfloat16(b.x), __float2bfloat16(b.y),
                 __float2bfloat16(b.z), __float2bfloat16(b.w)};
    return *(bf16x8*)t;
}

// ---------------------------------------------------------------------------
__global__ __launch_bounds__(256, 2) void k_persist(
    const float* __restrict__ xf, const bf16* __restrict__ kt,
    const bf16* __restrict__ wrct, const bf16* __restrict__ aggt,
    const float* __restrict__ bias, const float* __restrict__ scal,
    float* __restrict__ zpart, bf16* __restrict__ abuf,
    float* __restrict__ c32, bf16* __restrict__ obuf,
    float* __restrict__ out, unsigned* __restrict__ cnt)
{
    __shared__ float smem[5120];    // 20 KB, reused P1 / P3
    const int bid = blockIdx.x, tid = threadIdx.x;
    const int w = tid >> 6, lane = tid & 63;
    const int q = lane >> 4, ml = lane & 15;
    const int g = bid >> 2, j = bid & 3;     // N-group, K-chunk
    const int n0 = g * 80;                   // 80 cols (5 n-tiles) per group
    const int kh = w & 1, mh = w >> 1;       // wave: K-half, M-half
    unsigned bar = 0;

    // P1 invariant pointers
    const int isC = j >> 1;
    const bf16* hiP = abuf + (isC ? 2 : 0) * 65536;
    const bf16* loP = hiP + 65536;
    const int kl0 = (j & 1) * 512 + kh * 256;   // within h/c [0,1024)
    const int kc0 = isC * 1024 + kl0;           // within wrct K2
    const int kx  = j * 64 + kh * 32 + q * 8;   // x chunk

    for (int t = 0; t < TSTEPS; ++t) {
        // ================= P1: partial z =================
        f32x4 acc[2][5];
#pragma unroll
        for (int mt = 0; mt < 2; ++mt)
#pragma unroll
            for (int nt = 0; nt < 5; ++nt) acc[mt][nt] = (f32x4){0.f, 0.f, 0.f, 0.f};

#pragma unroll
        for (int it = 0; it < 8; ++it) {
            const int ko = it * 32 + q * 8;
            bf16x8 ah[2], al[2], b[5];
#pragma unroll
            for (int mt = 0; mt < 2; ++mt) {
                const int m = mh * 32 + mt * 16 + ml;
                ah[mt] = *(const bf16x8*)(hiP + m * U + kl0 + ko);
                al[mt] = *(const bf16x8*)(loP + m * U + kl0 + ko);
            }
#pragma unroll
            for (int nt = 0; nt < 5; ++nt)
                b[nt] = *(const bf16x8*)(wrct + (n0 + nt * 16 + ml) * K2 + kc0 + ko);
#pragma unroll
            for (int mt = 0; mt < 2; ++mt)
#pragma unroll
                for (int nt = 0; nt < 5; ++nt) {
                    acc[mt][nt] = __builtin_amdgcn_mfma_f32_16x16x32_bf16(
                        ah[mt], b[nt], acc[mt][nt], 0, 0, 0);
                    acc[mt][nt] = __builtin_amdgcn_mfma_f32_16x16x32_bf16(
                        al[mt], b[nt], acc[mt][nt], 0, 0, 0);
                }
        }
        {   // x @ kernel (K slice of 32)
            bf16x8 ax[2], b[5];
#pragma unroll
            for (int mt = 0; mt < 2; ++mt) {
                const int m = mh * 32 + mt * 16 + ml;
                ax[mt] = cvt8(xf + (m * TSTEPS + t) * DIM + kx);
            }
#pragma unroll
            for (int nt = 0; nt < 5; ++nt)
                b[nt] = *(const bf16x8*)(kt + (n0 + nt * 16 + ml) * DIM + kx);
#pragma unroll
            for (int mt = 0; mt < 2; ++mt)
#pragma unroll
                for (int nt = 0; nt < 5; ++nt)
                    acc[mt][nt] = __builtin_amdgcn_mfma_f32_16x16x32_bf16(
                        ax[mt], b[nt], acc[mt][nt], 0, 0, 0);
        }
        // cross-wave (K-half) reduce in LDS, then store partial
        if (kh == 1) {
#pragma unroll
            for (int mt = 0; mt < 2; ++mt)
#pragma unroll
                for (int nt = 0; nt < 5; ++nt)
                    *(f32x4*)&smem[((mh * 10 + mt * 5 + nt) * 64 + lane) * 4] = acc[mt][nt];
        }
        __syncthreads();
        if (kh == 0) {
            float* zp = zpart + j * ZP;
#pragma unroll
            for (int mt = 0; mt < 2; ++mt)
#pragma unroll
                for (int nt = 0; nt < 5; ++nt) {
                    f32x4 o = *(const f32x4*)&smem[((mh * 10 + mt * 5 + nt) * 64 + lane) * 4];
                    o += acc[mt][nt];
                    const int colN = n0 + nt * 16 + ml;
                    const float bv = (j == 3) ? bias[colN] : 0.f;
                    const int mrow = mh * 32 + mt * 16 + q * 4;
#pragma unroll
                    for (int r = 0; r < 4; ++r)
                        zp[(mrow + r) * N5 + colN] = o[r] + bv;
                }
        }
        bar += NBLK; gsync(cnt, tid, bar);

        // ================= P2: gates (1 wave per batch row) =================
        if (bid < BATCH && tid < 64) {
            const int l = tid;
            const int rb = bid * N5 + l * 16;
            float zu[16], zd[16], zn[16];
#pragma unroll
            for (int i = 0; i < 16; ++i) { zu[i] = 0.f; zd[i] = 0.f; zn[i] = 0.f; }
#pragma unroll
            for (int jj = 0; jj < 4; ++jj) {
                const float* zpr = zpart + jj * ZP + rb;
#pragma unroll
                for (int i4 = 0; i4 < 4; ++i4) {
                    const float4 a = *(const float4*)(zpr + i4 * 4);
                    const float4 b = *(const float4*)(zpr + U + i4 * 4);
                    const float4 c = *(const float4*)(zpr + 2 * U + i4 * 4);
                    zu[i4*4+0] += a.x; zu[i4*4+1] += a.y; zu[i4*4+2] += a.z; zu[i4*4+3] += a.w;
                    zd[i4*4+0] += b.x; zd[i4*4+1] += b.y; zd[i4*4+2] += b.z; zd[i4*4+3] += b.w;
                    zn[i4*4+0] += c.x; zn[i4*4+1] += c.y; zn[i4*4+2] += c.z; zn[i4*4+3] += c.w;
                }
            }
            // up = cumsum_l2r(softmax(zu))
            float m = zu[0];
#pragma unroll
            for (int i = 1; i < 16; ++i) m = fmaxf(m, zu[i]);
            m = wave_max(m);
            float e[16], run = 0.f;
#pragma unroll
            for (int i = 0; i < 16; ++i) { e[i] = __expf(zu[i] - m); run += e[i]; }
            float incl = wave_scan(run, l);
            const float tot = __shfl(incl, 63, 64);
            const float inv = 1.f / tot;
            float up[16], accp = incl - run;
#pragma unroll
            for (int i = 0; i < 16; ++i) { accp += e[i]; up[i] = accp * inv; }
            // down = suffix-cumsum(softmax(zd))
            float m2 = zd[0];
#pragma unroll
            for (int i = 1; i < 16; ++i) m2 = fmaxf(m2, zd[i]);
            m2 = wave_max(m2);
            float f[16], run2 = 0.f;
#pragma unroll
            for (int i = 0; i < 16; ++i) { f[i] = __expf(zd[i] - m2); run2 += f[i]; }
            float incl2 = wave_scan(run2, l);
            const float totd = __shfl(incl2, 63, 64);
            const float invd = 1.f / totd;
            float dn[16], sacc = totd - incl2;   // sum over lanes > l
#pragma unroll
            for (int i = 15; i >= 0; --i) { sacc += f[i]; dn[i] = sacc * invd; }
            // row dots
            float sdu = 0.f, sru = 0.f, sdr = 0.f;
#pragma unroll
            for (int i = 0; i < 16; ++i) {
                sdu += dn[i] * up[i]; sru += zn[i] * up[i]; sdr += dn[i] * zn[i];
            }
            const float du = wave_sum(sdu), ru = wave_sum(sru), dr = wave_sum(sdr);
            const float s_ud = scal[0], s_ur = scal[1], s_ru = scal[2],
                        s_rd = scal[3], s_du = scal[4], s_dr = scal[5];
            bf16* orow = obuf + bid * 3072 + l * 16;
#pragma unroll
            for (int i = 0; i < 16; ++i) {
                const float O1 = sigm(s_ud * up[i] * du) + sigm(s_ur * up[i] * ru);
                const float O2 = sigm(s_ru * zn[i] * ru) + sigm(s_rd * zn[i] * dr);
                const float O3 = sigm(s_du * dn[i] * du) + sigm(s_dr * dn[i] * dr);
                orow[i]         = __float2bfloat16(O1);
                orow[U + i]     = __float2bfloat16(O2);
                orow[2 * U + i] = __float2bfloat16(O3);
            }
        }
        bar += NBLK; gsync(cnt, tid, bar);

        // ================= P3: f-gate GEMM + state update =================
        if (bid < 64) {
            const int n0p = bid * 16;
            f32x4 acc2[4];
#pragma unroll
            for (int i = 0; i < 4; ++i) acc2[i] = (f32x4){0.f, 0.f, 0.f, 0.f};
            const int kbase = w * 768;
#pragma unroll 4
            for (int it = 0; it < 24; ++it) {
                const int kk = kbase + it * 32 + q * 8;
                bf16x8 a[4];
#pragma unroll
                for (int mi = 0; mi < 4; ++mi)
                    a[mi] = *(const bf16x8*)(obuf + (mi * 16 + ml) * 3072 + kk);
                const bf16x8 bb = *(const bf16x8*)(aggt + (n0p + ml) * 3072 + kk);
#pragma unroll
                for (int mi = 0; mi < 4; ++mi)
                    acc2[mi] = __builtin_amdgcn_mfma_f32_16x16x32_bf16(a[mi], bb, acc2[mi], 0, 0, 0);
            }
#pragma unroll
            for (int tile = 0; tile < 4; ++tile)
                *(f32x4*)&smem[((w * 4 + tile) * 64 + lane) * 4] = acc2[tile];
            __syncthreads();
            for (int idx = tid; idx < 1024; idx += 256) {
                const int tile = idx >> 8, rem = idx & 255, ln = rem >> 2, r = rem & 3;
                const float v = smem[(tile)*256 + ln * 4 + r] + smem[(4 + tile) * 256 + ln * 4 + r]
                              + smem[(8 + tile) * 256 + ln * 4 + r] + smem[(12 + tile) * 256 + ln * 4 + r];
                const int row = tile * 16 + (ln >> 4) * 4 + r;   // batch index
                const int col = n0p + (ln & 15);                 // u index
                float z3 = 0.f, z4 = 0.f;
#pragma unroll
                for (int jj = 0; jj < 4; ++jj) {
                    z3 += zpart[jj * ZP + row * N5 + 3 * U + col];
                    z4 += zpart[jj * ZP + row * N5 + 4 * U + col];
                }
                const float fg = sigm(v);
                const float cold = c32[row * U + col];
                const float cn = fg * cold + (1.f - fg) * tanhf(z4);
                const float hn = z3 * tanhf(cn);
                c32[row * U + col] = cn;
                const bf16 ch = __float2bfloat16(cn);
                const bf16 cl = __float2bfloat16(cn - __bfloat162float(ch));
                const bf16 hh = __float2bfloat16(hn);
                const bf16 hl = __float2bfloat16(hn - __bfloat162float(hh));
                abuf[0 * 65536 + row * U + col] = hh;
                abuf[1 * 65536 + row * U + col] = hl;
                abuf[2 * 65536 + row * U + col] = ch;
                abuf[3 * 65536 + row * U + col] = cl;
                out[(row * TSTEPS + t) * U + col] = hn;
            }
        }
        bar += NBLK; gsync(cnt, tid, bar);
    }
}

// ---------------------------------------------------------------------------
extern "C" void kernel_launch(void* const* d_in, const int* in_sizes, int n_in,
                              void* d_out, int out_size, void* d_ws, size_t ws_size,
                              hipStream_t stream) {
    (void)in_sizes; (void)n_in; (void)out_size; (void)ws_size;
    const float* x    = (const float*)d_in[0];
    const float* Wk   = (const float*)d_in[1];   // (256,5120)
    const float* Wr   = (const float*)d_in[2];   // (1024,5120)
    const float* Wc   = (const float*)d_in[3];   // (1024,5120)
    const float* bias = (const float*)d_in[4];   // (5120)
    const float* agg  = (const float*)d_in[5];   // (3072,1024)

    char* ws = (char*)d_ws;
    bf16*     wrct  = (bf16*)(ws + OFF_WRC);
    bf16*     kt    = (bf16*)(ws + OFF_KT);
    bf16*     aggt  = (bf16*)(ws + OFF_AGGT);
    float*    zpart = (float*)(ws + OFF_ZPART);
    bf16*     abuf  = (bf16*)(ws + OFF_ABUF);
    float*    c32   = (float*)(ws + OFF_C32);
    bf16*     obuf  = (bf16*)(ws + OFF_OBUF);
    float*    scal  = (float*)(ws + OFF_SCAL);
    unsigned* cnt   = (unsigned*)(ws + OFF_SYNC);
    float*    outp  = (float*)d_out;

    hipMemsetAsync(abuf, 0, 4 * 65536 * sizeof(bf16), stream);
    hipMemsetAsync(c32, 0, BATCH * U * sizeof(float), stream);
    hipMemsetAsync(cnt, 0, 64, stream);

    k_transpose<<<dim3(5120 / 64, 1024 / 64), 256, 0, stream>>>(Wr, wrct, 5120, 2048, 0);
    k_transpose<<<dim3(5120 / 64, 1024 / 64), 256, 0, stream>>>(Wc, wrct, 5120, 2048, 1024);
    k_transpose<<<dim3(5120 / 64, 256 / 64),  256, 0, stream>>>(Wk, kt,   5120, 256, 0);
    k_transpose<<<dim3(1024 / 64, 3072 / 64), 256, 0, stream>>>(agg, aggt, 1024, 3072, 0);

    AttPtrs ap;
    for (int i = 0; i < 12; ++i) ap.p[i] = (const float*)d_in[6 + i];
    k_scal<<<1, 256, 0, stream>>>(ap, scal);

    void* args[] = {&x, &kt, &wrct, &aggt, &bias, &scal,
                    &zpart, &abuf, &c32, &obuf, &outp, &cnt};
    hipLaunchCooperativeKernel((const void*)k_persist, dim3(NBLK), dim3(256),
                               args, 0, stream);
}